// Round 1
// baseline (268.527 us; speedup 1.0000x reference)
//
#include <hip/hip_runtime.h>

#define L_NODES 100000
#define NFEAT   256
#define JDIM    128

typedef __bf16 bf16x8 __attribute__((ext_vector_type(8)));
typedef __bf16 bf16x4 __attribute__((ext_vector_type(4)));
typedef float  floatx4 __attribute__((ext_vector_type(4)));

// ---------------------------------------------------------------------------
// Prep:
//   WtH [128][256]: WtH[n][k]  = bf16(W_h1[k][n])
//   WtG2[256][128]: n<128: Wg[k][n]   (U cols);  n>=128: Wg[128+k][n-128] (V cols)
//     rows 128.. of WtG2 double as WtGv[n][k]=Wg[128+k][n] for k_gfinal.
// ---------------------------------------------------------------------------
__global__ __launch_bounds__(256) void k_prep(
    const float* __restrict__ Wh, const float* __restrict__ Wg,
    __bf16* __restrict__ WtH, __bf16* __restrict__ WtG2)
{
    int i = blockIdx.x * 256 + threadIdx.x;   // 32768
    int n = i >> 8, k = i & 255;
    WtH[i] = (__bf16)Wh[k * JDIM + n];
    int n2 = i >> 7, k2 = i & 127;
    WtG2[i] = (n2 < 128) ? (__bf16)Wg[k2 * JDIM + n2]
                         : (__bf16)Wg[(128 + k2) * JDIM + (n2 - 128)];
}

// ---------------------------------------------------------------------------
// Kernel 1 (fused h1+uv).  R12 change: Hs and the output restage now ALIAS
// the As buffer (disjoint lifetimes, enforced by 2 extra barriers).  LDS
// 51.2 KB -> 33.8 KB so 4 blocks/CU fit instead of 2 -> latency hiding via
// cross-block phase overlap.
// ---------------------------------------------------------------------------
__global__ __launch_bounds__(256) void k_h1uv(
    const float* __restrict__ X, const __bf16* __restrict__ WtH,
    const __bf16* __restrict__ WtG2, const float* __restrict__ b,
    __bf16* __restrict__ U, __bf16* __restrict__ V)
{
    // Single 33.8 KB buffer.  Phases:
    //   [stage X]  As   64x264 bf16 (stride 264, 2-way-free bank pattern)
    //   [h-act]    Hs   64x136 bf16 (stride 136)   -- aliases As
    //   [restage]  Os   64x264 bf16                -- aliases Hs
    __shared__ __bf16 Sm[64 * 264];

    const int tid  = threadIdx.x;
    const int row0 = blockIdx.x * 64;
    const int wave = tid >> 6, lane = tid & 63;
    const int lm = lane & 15, lq = lane >> 4;

    bf16x8 b1[2][8];
    #pragma unroll
    for (int nt = 0; nt < 2; ++nt) {
        int ntg = wave * 2 + nt;
        #pragma unroll
        for (int ks = 0; ks < 8; ++ks)
            b1[nt][ks] = *(const bf16x8*)(WtH + (size_t)(ntg * 16 + lm) * 256 + ks * 32 + lq * 8);
    }

    #pragma unroll
    for (int it = 0; it < 16; ++it) {
        int f4  = it * 256 + tid;
        int row = f4 >> 6, c4 = f4 & 63;
        int grow = row0 + row; if (grow >= L_NODES) grow = L_NODES - 1;
        float4 v = *(const float4*)(X + (size_t)grow * NFEAT + c4 * 4);
        bf16x4 o; o[0]=(__bf16)v.x; o[1]=(__bf16)v.y; o[2]=(__bf16)v.z; o[3]=(__bf16)v.w;
        *(bf16x4*)&Sm[row * 264 + c4 * 4] = o;
    }
    __syncthreads();

    floatx4 acc1[4][2] = {};
    #pragma unroll
    for (int ks = 0; ks < 8; ++ks) {
        bf16x8 af[4];
        #pragma unroll
        for (int t = 0; t < 4; ++t)
            af[t] = *(const bf16x8*)&Sm[(t * 16 + lm) * 264 + ks * 32 + lq * 8];
        #pragma unroll
        for (int t = 0; t < 4; ++t)
            #pragma unroll
            for (int nt = 0; nt < 2; ++nt)
                acc1[t][nt] = __builtin_amdgcn_mfma_f32_16x16x32_bf16(
                    af[t], b1[nt][ks], acc1[t][nt], 0, 0, 0);
    }

    bf16x8 b2[4][4];
    #pragma unroll
    for (int nt = 0; nt < 4; ++nt) {
        int ntg = wave * 4 + nt;
        #pragma unroll
        for (int ks = 0; ks < 4; ++ks)
            b2[nt][ks] = *(const bf16x8*)(WtG2 + (size_t)(ntg * 16 + lm) * 128 + ks * 32 + lq * 8);
    }

    __syncthreads();   // NEW: all As reads done before Hs (alias) is written

    #pragma unroll
    for (int nt = 0; nt < 2; ++nt) {
        int col = (wave * 2 + nt) * 16 + lm;
        float bias = b[col];
        #pragma unroll
        for (int t = 0; t < 4; ++t)
            #pragma unroll
            for (int p = 0; p < 4; ++p)
                Sm[(t * 16 + lq * 4 + p) * 136 + col] =
                    (__bf16)fmaxf(acc1[t][nt][p] + bias, 0.f);
    }
    __syncthreads();

    floatx4 acc2[4][4] = {};
    #pragma unroll
    for (int ks = 0; ks < 4; ++ks) {
        bf16x8 af[4];
        #pragma unroll
        for (int t = 0; t < 4; ++t)
            af[t] = *(const bf16x8*)&Sm[(t * 16 + lm) * 136 + ks * 32 + lq * 8];
        #pragma unroll
        for (int t = 0; t < 4; ++t)
            #pragma unroll
            for (int nt = 0; nt < 4; ++nt)
                acc2[t][nt] = __builtin_amdgcn_mfma_f32_16x16x32_bf16(
                    af[t], b2[nt][ks], acc2[t][nt], 0, 0, 0);
    }

    __syncthreads();   // NEW: all Hs reads done before output restage (alias)

    #pragma unroll
    for (int nt = 0; nt < 4; ++nt) {
        int col = (wave * 4 + nt) * 16 + lm;
        #pragma unroll
        for (int t = 0; t < 4; ++t)
            #pragma unroll
            for (int p = 0; p < 4; ++p)
                Sm[(t * 16 + lq * 4 + p) * 264 + col] = (__bf16)acc2[t][nt][p];
    }
    __syncthreads();

    #pragma unroll
    for (int it = 0; it < 8; ++it) {
        int fid = it * 256 + tid;
        int row = fid >> 5, c8 = fid & 31;
        int grow = row0 + row;
        if (grow < L_NODES) {
            int col = c8 * 8;
            bf16x8 v = *(bf16x8*)&Sm[row * 264 + col];
            if (col < 128) *(bf16x8*)(U + (size_t)grow * JDIM + col) = v;
            else           *(bf16x8*)(V + (size_t)grow * JDIM + (col - 128)) = v;
        }
    }
}

// ---------------------------------------------------------------------------
// Kernel 2 (FUSED gather + final): per 64-row block:
//   phase A: E1[r] = relu(mean_s relu(U[idx0[s,r]] + V[idx1[s,r]] + bg))
//            computed straight into LDS (E1 never touches HBM).
//   phase B: E2 = relu(U + E1 @ Wg_bot + bg); out = E2 @ Wf + bf  (MFMA K=128)
// ---------------------------------------------------------------------------
__global__ __launch_bounds__(256) void k_gfinal(
    const __bf16* __restrict__ U, const __bf16* __restrict__ V,
    const __bf16* __restrict__ WtGv, const float* __restrict__ bg,
    const float* __restrict__ Wf, const float* __restrict__ bf,
    const int* __restrict__ idx0, const int* __restrict__ idx1,
    float* __restrict__ out)
{
    __shared__ int    sidx0[8][64], sidx1[8][64];   // 4 KB
    __shared__ __bf16 E1s[64 * 136];                // 17.4 KB
    __shared__ __bf16 Us [64 * 136];                // 17.4 KB
    __shared__ float  part[4][64][2];               // 2 KB

    const int tid  = threadIdx.x;
    const int row0 = blockIdx.x * 64;
    const int wave = tid >> 6, lane = tid & 63;
    const int lm = lane & 15, lq = lane >> 4;

    // B panel resident: 8 frags = 32 VGPR
    bf16x8 b3[2][4];
    #pragma unroll
    for (int nt = 0; nt < 2; ++nt) {
        int ntg = wave * 2 + nt;
        #pragma unroll
        for (int ks = 0; ks < 4; ++ks)
            b3[nt][ks] = *(const bf16x8*)(WtGv + (size_t)(ntg * 16 + lm) * 128 + ks * 32 + lq * 8);
    }

    // stage indices (1024 ints, 4/thread) and U tile (4 bf16x8/thread)
    #pragma unroll
    for (int it = 0; it < 4; ++it) {
        int fid = it * 256 + tid;                 // 0..1023
        int m = fid >> 9, rem = fid & 511;
        int s = rem >> 6, il = rem & 63;
        int gr = row0 + il; if (gr >= L_NODES) gr = L_NODES - 1;
        int val = (m ? idx1 : idx0)[(size_t)s * L_NODES + gr];
        if (m) sidx1[s][il] = val; else sidx0[s][il] = val;
    }
    #pragma unroll
    for (int it = 0; it < 4; ++it) {
        int fid = it * 256 + tid;                 // 0..1023
        int r = fid >> 4, c8 = fid & 15;
        int g = row0 + r; if (g >= L_NODES) g = L_NODES - 1;
        *(bf16x8*)&Us[r * 136 + c8 * 8] = *(const bf16x8*)(U + (size_t)g * JDIM + c8 * 8);
    }
    __syncthreads();

    // ---- phase A: gather-add into E1s ----
    {
        const int c0 = (tid & 15) * 8;            // col chunk
        const int rb = tid >> 4;                  // row base 0..15 (+16k)
        float bias[8];
        *(float4*)&bias[0] = *(const float4*)(bg + c0);
        *(float4*)&bias[4] = *(const float4*)(bg + c0 + 4);

        float acc[4][8] = {};
        #pragma unroll
        for (int s = 0; s < 8; ++s) {
            #pragma unroll
            for (int rr = 0; rr < 4; ++rr) {
                int r = rb + rr * 16;
                int a0 = sidx0[s][r], a1 = sidx1[s][r];
                bf16x8 u = *(const bf16x8*)(U + (size_t)a0 * JDIM + c0);
                bf16x8 v = *(const bf16x8*)(V + (size_t)a1 * JDIM + c0);
                #pragma unroll
                for (int p = 0; p < 8; ++p)
                    acc[rr][p] += fmaxf((float)u[p] + (float)v[p] + bias[p], 0.f);
            }
        }
        #pragma unroll
        for (int rr = 0; rr < 4; ++rr) {
            int r = rb + rr * 16;
            bf16x8 o;
            #pragma unroll
            for (int p = 0; p < 8; ++p)
                o[p] = (__bf16)fmaxf(acc[rr][p] * 0.125f, 0.f);
            *(bf16x8*)&E1s[r * 136 + c0] = o;
        }
    }
    __syncthreads();

    // ---- phase B: E2 = relu(U + E1 @ Wg_bot + bg); head ----
    floatx4 acc[4][2] = {};
    #pragma unroll
    for (int ks = 0; ks < 4; ++ks) {
        bf16x8 af[4];
        #pragma unroll
        for (int t = 0; t < 4; ++t)
            af[t] = *(const bf16x8*)&E1s[(t * 16 + lm) * 136 + ks * 32 + lq * 8];
        #pragma unroll
        for (int t = 0; t < 4; ++t)
            #pragma unroll
            for (int nt = 0; nt < 2; ++nt)
                acc[t][nt] = __builtin_amdgcn_mfma_f32_16x16x32_bf16(
                    af[t], b3[nt][ks], acc[t][nt], 0, 0, 0);
    }

    float bias[2], wf0[2], wf1[2];
    #pragma unroll
    for (int nt = 0; nt < 2; ++nt) {
        int col = (wave * 2 + nt) * 16 + lm;
        bias[nt] = bg[col];
        wf0[nt] = Wf[col * 2 + 0];
        wf1[nt] = Wf[col * 2 + 1];
    }
    #pragma unroll
    for (int t = 0; t < 4; ++t) {
        float p0[4], p1[4];
        #pragma unroll
        for (int p = 0; p < 4; ++p) {
            int r = t * 16 + lq * 4 + p;
            float a0 = 0.f, a1 = 0.f;
            #pragma unroll
            for (int nt = 0; nt < 2; ++nt) {
                int col = (wave * 2 + nt) * 16 + lm;
                float e2 = fmaxf((float)Us[r * 136 + col] + acc[t][nt][p] + bias[nt], 0.f);
                a0 = fmaf(e2, wf0[nt], a0);
                a1 = fmaf(e2, wf1[nt], a1);
            }
            p0[p] = a0; p1[p] = a1;
        }
        #pragma unroll
        for (int m = 1; m <= 8; m <<= 1)
            #pragma unroll
            for (int p = 0; p < 4; ++p) {
                p0[p] += __shfl_xor(p0[p], m, 16);
                p1[p] += __shfl_xor(p1[p], m, 16);
            }
        if (lm == 0)
            #pragma unroll
            for (int p = 0; p < 4; ++p) {
                part[wave][t * 16 + lq * 4 + p][0] = p0[p];
                part[wave][t * 16 + lq * 4 + p][1] = p1[p];
            }
    }
    __syncthreads();

    if (tid < 128) {
        int row = tid >> 1, o = tid & 1;
        int grow = row0 + row;
        if (grow < L_NODES)
            out[(size_t)grow * 2 + o] =
                part[0][row][o] + part[1][row][o] + part[2][row][o] + part[3][row][o] + bf[o];
    }
}

// ---------------------------------------------------------------------------
extern "C" void kernel_launch(void* const* d_in, const int* in_sizes, int n_in,
                              void* d_out, int out_size, void* d_ws, size_t ws_size,
                              hipStream_t stream) {
    const float* X    = (const float*)d_in[0];
    const float* W_h1 = (const float*)d_in[1];
    const float* b_h1 = (const float*)d_in[2];
    const float* W_g1 = (const float*)d_in[3];
    const float* b_g1 = (const float*)d_in[4];
    const float* W_f  = (const float*)d_in[5];
    const float* b_f  = (const float*)d_in[6];
    const int*   idx0 = (const int*)d_in[7];
    const int*   idx1 = (const int*)d_in[8];
    float* out = (float*)d_out;

    __bf16* U    = (__bf16*)d_ws;                         // 25.6 MB
    __bf16* V    = U   + (size_t)L_NODES * JDIM;          // 25.6 MB
    __bf16* WtH  = V   + (size_t)L_NODES * JDIM;          // 64 KB
    __bf16* WtG2 = WtH + 32768;                           // 64 KB
    __bf16* WtGv = WtG2 + 128 * 128;                      // alias: rows 128.. of WtG2

    k_prep<<<128, 256, 0, stream>>>(W_h1, W_g1, WtH, WtG2);
    k_h1uv<<<(L_NODES + 63) / 64, 256, 0, stream>>>(X, WtH, WtG2, b_h1, U, V);
    k_gfinal<<<(L_NODES + 63) / 64, 256, 0, stream>>>(U, V, WtGv, b_g1, W_f, b_f,
                                                      idx0, idx1, out);
}

// Round 2
// 266.321 us; speedup vs baseline: 1.0083x; 1.0083x over previous
//
#include <hip/hip_runtime.h>

#define L_NODES 100000
#define NFEAT   256
#define JDIM    128

typedef __bf16 bf16x8 __attribute__((ext_vector_type(8)));
typedef __bf16 bf16x4 __attribute__((ext_vector_type(4)));
typedef float  floatx4 __attribute__((ext_vector_type(4)));

// ---------------------------------------------------------------------------
// Prep:
//   WtH [128][256]: WtH[n][k]  = bf16(W_h1[k][n])
//   WtG2[256][128]: n<128: Wg[k][n]   (U cols);  n>=128: Wg[128+k][n-128] (V cols)
//     rows 128.. of WtG2 double as WtGv[n][k]=Wg[128+k][n] for k_gfinal.
// ---------------------------------------------------------------------------
__global__ __launch_bounds__(256) void k_prep(
    const float* __restrict__ Wh, const float* __restrict__ Wg,
    __bf16* __restrict__ WtH, __bf16* __restrict__ WtG2)
{
    int i = blockIdx.x * 256 + threadIdx.x;   // 32768
    int n = i >> 8, k = i & 255;
    WtH[i] = (__bf16)Wh[k * JDIM + n];
    int n2 = i >> 7, k2 = i & 127;
    WtG2[i] = (n2 < 128) ? (__bf16)Wg[k2 * JDIM + n2]
                         : (__bf16)Wg[(128 + k2) * JDIM + (n2 - 128)];
}

// ---------------------------------------------------------------------------
// Kernel 1 (fused h1+uv).  Hs and the output restage ALIAS the As buffer
// (disjoint lifetimes, enforced by barriers).  LDS 33.8 KB -> 4 blocks/CU.
// ---------------------------------------------------------------------------
__global__ __launch_bounds__(256) void k_h1uv(
    const float* __restrict__ X, const __bf16* __restrict__ WtH,
    const __bf16* __restrict__ WtG2, const float* __restrict__ b,
    __bf16* __restrict__ U, __bf16* __restrict__ V)
{
    __shared__ __bf16 Sm[64 * 264];

    const int tid  = threadIdx.x;
    const int row0 = blockIdx.x * 64;
    const int wave = tid >> 6, lane = tid & 63;
    const int lm = lane & 15, lq = lane >> 4;

    bf16x8 b1[2][8];
    #pragma unroll
    for (int nt = 0; nt < 2; ++nt) {
        int ntg = wave * 2 + nt;
        #pragma unroll
        for (int ks = 0; ks < 8; ++ks)
            b1[nt][ks] = *(const bf16x8*)(WtH + (size_t)(ntg * 16 + lm) * 256 + ks * 32 + lq * 8);
    }

    #pragma unroll
    for (int it = 0; it < 16; ++it) {
        int f4  = it * 256 + tid;
        int row = f4 >> 6, c4 = f4 & 63;
        int grow = row0 + row; if (grow >= L_NODES) grow = L_NODES - 1;
        float4 v = *(const float4*)(X + (size_t)grow * NFEAT + c4 * 4);
        bf16x4 o; o[0]=(__bf16)v.x; o[1]=(__bf16)v.y; o[2]=(__bf16)v.z; o[3]=(__bf16)v.w;
        *(bf16x4*)&Sm[row * 264 + c4 * 4] = o;
    }
    __syncthreads();

    floatx4 acc1[4][2] = {};
    #pragma unroll
    for (int ks = 0; ks < 8; ++ks) {
        bf16x8 af[4];
        #pragma unroll
        for (int t = 0; t < 4; ++t)
            af[t] = *(const bf16x8*)&Sm[(t * 16 + lm) * 264 + ks * 32 + lq * 8];
        #pragma unroll
        for (int t = 0; t < 4; ++t)
            #pragma unroll
            for (int nt = 0; nt < 2; ++nt)
                acc1[t][nt] = __builtin_amdgcn_mfma_f32_16x16x32_bf16(
                    af[t], b1[nt][ks], acc1[t][nt], 0, 0, 0);
    }

    bf16x8 b2[4][4];
    #pragma unroll
    for (int nt = 0; nt < 4; ++nt) {
        int ntg = wave * 4 + nt;
        #pragma unroll
        for (int ks = 0; ks < 4; ++ks)
            b2[nt][ks] = *(const bf16x8*)(WtG2 + (size_t)(ntg * 16 + lm) * 128 + ks * 32 + lq * 8);
    }

    __syncthreads();   // all As reads done before Hs (alias) is written

    #pragma unroll
    for (int nt = 0; nt < 2; ++nt) {
        int col = (wave * 2 + nt) * 16 + lm;
        float bias = b[col];
        #pragma unroll
        for (int t = 0; t < 4; ++t)
            #pragma unroll
            for (int p = 0; p < 4; ++p)
                Sm[(t * 16 + lq * 4 + p) * 136 + col] =
                    (__bf16)fmaxf(acc1[t][nt][p] + bias, 0.f);
    }
    __syncthreads();

    floatx4 acc2[4][4] = {};
    #pragma unroll
    for (int ks = 0; ks < 4; ++ks) {
        bf16x8 af[4];
        #pragma unroll
        for (int t = 0; t < 4; ++t)
            af[t] = *(const bf16x8*)&Sm[(t * 16 + lm) * 136 + ks * 32 + lq * 8];
        #pragma unroll
        for (int t = 0; t < 4; ++t)
            #pragma unroll
            for (int nt = 0; nt < 4; ++nt)
                acc2[t][nt] = __builtin_amdgcn_mfma_f32_16x16x32_bf16(
                    af[t], b2[nt][ks], acc2[t][nt], 0, 0, 0);
    }

    __syncthreads();   // all Hs reads done before output restage (alias)

    #pragma unroll
    for (int nt = 0; nt < 4; ++nt) {
        int col = (wave * 4 + nt) * 16 + lm;
        #pragma unroll
        for (int t = 0; t < 4; ++t)
            #pragma unroll
            for (int p = 0; p < 4; ++p)
                Sm[(t * 16 + lq * 4 + p) * 264 + col] = (__bf16)acc2[t][nt][p];
    }
    __syncthreads();

    #pragma unroll
    for (int it = 0; it < 8; ++it) {
        int fid = it * 256 + tid;
        int row = fid >> 5, c8 = fid & 31;
        int grow = row0 + row;
        if (grow < L_NODES) {
            int col = c8 * 8;
            bf16x8 v = *(bf16x8*)&Sm[row * 264 + col];
            if (col < 128) *(bf16x8*)(U + (size_t)grow * JDIM + col) = v;
            else           *(bf16x8*)(V + (size_t)grow * JDIM + (col - 128)) = v;
        }
    }
}

// ---------------------------------------------------------------------------
// Kernel 2 (fused gather + final).  R13 changes:
//   - part[] aliases sidx[] (disjoint lifetimes across the phase-A barrier)
//     -> LDS 40.96 KB -> 38.9 KB -> 4 blocks/CU instead of 3.
//   - __launch_bounds__(256, 4) pins VGPR <= 128 so 4 waves/SIMD fit.
//   - phase A gather is a 2-deep software pipeline over s (named double
//     buffers, static indexing) -> 16 loads in flight per thread.
//   - b3 (Wg_bot panel) is loaded AFTER phase A: it's phase-B-only and was
//     holding 32 VGPRs through the gather.
// ---------------------------------------------------------------------------
__global__ __launch_bounds__(256, 4) void k_gfinal(
    const __bf16* __restrict__ U, const __bf16* __restrict__ V,
    const __bf16* __restrict__ WtGv, const float* __restrict__ bg,
    const float* __restrict__ Wf, const float* __restrict__ bf,
    const int* __restrict__ idx0, const int* __restrict__ idx1,
    float* __restrict__ out)
{
    __shared__ int    sidx[2][8][64];               // 4 KB; part[] aliases this
    __shared__ __bf16 E1s[64 * 136];                // 17.4 KB
    __shared__ __bf16 Us [64 * 136];                // 17.4 KB
    float (*part)[64][2] = (float (*)[64][2])&sidx[0][0][0];   // 2 KB alias

    const int tid  = threadIdx.x;
    const int row0 = blockIdx.x * 64;
    const int wave = tid >> 6, lane = tid & 63;
    const int lm = lane & 15, lq = lane >> 4;

    // stage indices (1024 ints, 4/thread) and U tile (4 bf16x8/thread)
    #pragma unroll
    for (int it = 0; it < 4; ++it) {
        int fid = it * 256 + tid;                 // 0..1023
        int m = fid >> 9, rem = fid & 511;
        int s = rem >> 6, il = rem & 63;
        int gr = row0 + il; if (gr >= L_NODES) gr = L_NODES - 1;
        sidx[m][s][il] = (m ? idx1 : idx0)[(size_t)s * L_NODES + gr];
    }
    #pragma unroll
    for (int it = 0; it < 4; ++it) {
        int fid = it * 256 + tid;                 // 0..1023
        int r = fid >> 4, c8 = fid & 15;
        int g = row0 + r; if (g >= L_NODES) g = L_NODES - 1;
        *(bf16x8*)&Us[r * 136 + c8 * 8] = *(const bf16x8*)(U + (size_t)g * JDIM + c8 * 8);
    }
    __syncthreads();

    // ---- phase A: gather-add into E1s (2-deep pipelined) ----
    {
        const int c0 = (tid & 15) * 8;            // col chunk
        const int rb = tid >> 4;                  // row base 0..15 (+16k)
        float bias[8];
        *(float4*)&bias[0] = *(const float4*)(bg + c0);
        *(float4*)&bias[4] = *(const float4*)(bg + c0 + 4);

        float acc[4][8] = {};
        bf16x8 uA[4], vA[4], uB[4], vB[4];

        auto LOADP = [&](int s, bf16x8 (&uu)[4], bf16x8 (&vv)[4]) {
            #pragma unroll
            for (int rr = 0; rr < 4; ++rr) {
                int r = rb + rr * 16;
                int a0 = sidx[0][s][r], a1 = sidx[1][s][r];
                uu[rr] = *(const bf16x8*)(U + (size_t)a0 * JDIM + c0);
                vv[rr] = *(const bf16x8*)(V + (size_t)a1 * JDIM + c0);
            }
        };
        auto ACCUM = [&](bf16x8 (&uu)[4], bf16x8 (&vv)[4]) {
            #pragma unroll
            for (int rr = 0; rr < 4; ++rr)
                #pragma unroll
                for (int p = 0; p < 8; ++p)
                    acc[rr][p] += fmaxf((float)uu[rr][p] + (float)vv[rr][p] + bias[p], 0.f);
        };

        LOADP(0, uA, vA);
        #pragma unroll
        for (int s = 0; s < 8; ++s) {
            if ((s & 1) == 0) {
                if (s < 7) LOADP(s + 1, uB, vB);
                ACCUM(uA, vA);
            } else {
                if (s < 7) LOADP(s + 1, uA, vA);
                ACCUM(uB, vB);
            }
        }

        #pragma unroll
        for (int rr = 0; rr < 4; ++rr) {
            int r = rb + rr * 16;
            bf16x8 o;
            #pragma unroll
            for (int p = 0; p < 8; ++p)
                o[p] = (__bf16)fmaxf(acc[rr][p] * 0.125f, 0.f);
            *(bf16x8*)&E1s[r * 136 + c0] = o;
        }
    }
    __syncthreads();   // also closes all sidx reads before part[] writes

    // B panel (phase-B-only): load now so it doesn't hold VGPRs in phase A
    bf16x8 b3[2][4];
    #pragma unroll
    for (int nt = 0; nt < 2; ++nt) {
        int ntg = wave * 2 + nt;
        #pragma unroll
        for (int ks = 0; ks < 4; ++ks)
            b3[nt][ks] = *(const bf16x8*)(WtGv + (size_t)(ntg * 16 + lm) * 128 + ks * 32 + lq * 8);
    }

    // ---- phase B: E2 = relu(U + E1 @ Wg_bot + bg); head ----
    floatx4 acc[4][2] = {};
    #pragma unroll
    for (int ks = 0; ks < 4; ++ks) {
        bf16x8 af[4];
        #pragma unroll
        for (int t = 0; t < 4; ++t)
            af[t] = *(const bf16x8*)&E1s[(t * 16 + lm) * 136 + ks * 32 + lq * 8];
        #pragma unroll
        for (int t = 0; t < 4; ++t)
            #pragma unroll
            for (int nt = 0; nt < 2; ++nt)
                acc[t][nt] = __builtin_amdgcn_mfma_f32_16x16x32_bf16(
                    af[t], b3[nt][ks], acc[t][nt], 0, 0, 0);
    }

    float bias[2], wf0[2], wf1[2];
    #pragma unroll
    for (int nt = 0; nt < 2; ++nt) {
        int col = (wave * 2 + nt) * 16 + lm;
        bias[nt] = bg[col];
        wf0[nt] = Wf[col * 2 + 0];
        wf1[nt] = Wf[col * 2 + 1];
    }
    #pragma unroll
    for (int t = 0; t < 4; ++t) {
        float p0[4], p1[4];
        #pragma unroll
        for (int p = 0; p < 4; ++p) {
            int r = t * 16 + lq * 4 + p;
            float a0 = 0.f, a1 = 0.f;
            #pragma unroll
            for (int nt = 0; nt < 2; ++nt) {
                int col = (wave * 2 + nt) * 16 + lm;
                float e2 = fmaxf((float)Us[r * 136 + col] + acc[t][nt][p] + bias[nt], 0.f);
                a0 = fmaf(e2, wf0[nt], a0);
                a1 = fmaf(e2, wf1[nt], a1);
            }
            p0[p] = a0; p1[p] = a1;
        }
        #pragma unroll
        for (int m = 1; m <= 8; m <<= 1)
            #pragma unroll
            for (int p = 0; p < 4; ++p) {
                p0[p] += __shfl_xor(p0[p], m, 16);
                p1[p] += __shfl_xor(p1[p], m, 16);
            }
        if (lm == 0)
            #pragma unroll
            for (int p = 0; p < 4; ++p) {
                part[wave][t * 16 + lq * 4 + p][0] = p0[p];
                part[wave][t * 16 + lq * 4 + p][1] = p1[p];
            }
    }
    __syncthreads();

    if (tid < 128) {
        int row = tid >> 1, o = tid & 1;
        int grow = row0 + row;
        if (grow < L_NODES)
            out[(size_t)grow * 2 + o] =
                part[0][row][o] + part[1][row][o] + part[2][row][o] + part[3][row][o] + bf[o];
    }
}

// ---------------------------------------------------------------------------
extern "C" void kernel_launch(void* const* d_in, const int* in_sizes, int n_in,
                              void* d_out, int out_size, void* d_ws, size_t ws_size,
                              hipStream_t stream) {
    const float* X    = (const float*)d_in[0];
    const float* W_h1 = (const float*)d_in[1];
    const float* b_h1 = (const float*)d_in[2];
    const float* W_g1 = (const float*)d_in[3];
    const float* b_g1 = (const float*)d_in[4];
    const float* W_f  = (const float*)d_in[5];
    const float* b_f  = (const float*)d_in[6];
    const int*   idx0 = (const int*)d_in[7];
    const int*   idx1 = (const int*)d_in[8];
    float* out = (float*)d_out;

    __bf16* U    = (__bf16*)d_ws;                         // 25.6 MB
    __bf16* V    = U   + (size_t)L_NODES * JDIM;          // 25.6 MB
    __bf16* WtH  = V   + (size_t)L_NODES * JDIM;          // 64 KB
    __bf16* WtG2 = WtH + 32768;                           // 64 KB
    __bf16* WtGv = WtG2 + 128 * 128;                      // alias: rows 128.. of WtG2

    k_prep<<<128, 256, 0, stream>>>(W_h1, W_g1, WtH, WtG2);
    k_h1uv<<<(L_NODES + 63) / 64, 256, 0, stream>>>(X, WtH, WtG2, b_h1, U, V);
    k_gfinal<<<(L_NODES + 63) / 64, 256, 0, stream>>>(U, V, WtGv, b_g1, W_f, b_f,
                                                      idx0, idx1, out);
}

// Round 3
// 258.306 us; speedup vs baseline: 1.0396x; 1.0310x over previous
//
#include <hip/hip_runtime.h>

#define L_NODES 100000
#define NFEAT   256
#define JDIM    128

typedef __bf16 bf16x8 __attribute__((ext_vector_type(8)));
typedef __bf16 bf16x4 __attribute__((ext_vector_type(4)));
typedef float  floatx4 __attribute__((ext_vector_type(4)));

// ---------------------------------------------------------------------------
// Prep:
//   WtH [128][256]: WtH[n][k]  = bf16(W_h1[k][n])
//   WtG2[256][128]: n<128: Wg[k][n]   (U cols);  n>=128: Wg[128+k][n-128] (V cols)
//     rows 128.. of WtG2 double as WtGv[n][k]=Wg[128+k][n] for k_gfinal.
// ---------------------------------------------------------------------------
__global__ __launch_bounds__(256) void k_prep(
    const float* __restrict__ Wh, const float* __restrict__ Wg,
    __bf16* __restrict__ WtH, __bf16* __restrict__ WtG2)
{
    int i = blockIdx.x * 256 + threadIdx.x;   // 32768
    int n = i >> 8, k = i & 255;
    WtH[i] = (__bf16)Wh[k * JDIM + n];
    int n2 = i >> 7, k2 = i & 127;
    WtG2[i] = (n2 < 128) ? (__bf16)Wg[k2 * JDIM + n2]
                         : (__bf16)Wg[(128 + k2) * JDIM + (n2 - 128)];
}

// ---------------------------------------------------------------------------
// Kernel 1 (fused h1+uv).  R14: occupancy was REGISTER-capped (2 waves/SIMD;
// VGPR+AGPR unified on gfx950 — b1+b2+acc1+acc2 resident ~200+ regs), not
// LDS-capped.  Changes:
//   - __launch_bounds__(256, 3): cap allocation at <=170 regs -> 3 waves/SIMD.
//   - phase 2 split into two nt-halves: b2 half-panel (32 regs) + acc half
//     (32 regs) just-in-time, results flushed to LDS per half.
//   - Hs is its own buffer; output restage aliases As only.  LDS = 51.2 KB
//     -> exactly 3 blocks/CU, matching the register target.
// ---------------------------------------------------------------------------
__global__ __launch_bounds__(256, 3) void k_h1uv(
    const float* __restrict__ X, const __bf16* __restrict__ WtH,
    const __bf16* __restrict__ WtG2, const float* __restrict__ b,
    __bf16* __restrict__ U, __bf16* __restrict__ V)
{
    __shared__ __bf16 Sm[64 * 264];   // X tile (As); later output restage (Os)
    __shared__ __bf16 Hs[64 * 136];   // H activations

    const int tid  = threadIdx.x;
    const int row0 = blockIdx.x * 64;
    const int wave = tid >> 6, lane = tid & 63;
    const int lm = lane & 15, lq = lane >> 4;

    // stage X tile (16 float4/thread, coalesced: one wave = one 1KB row chunk)
    #pragma unroll
    for (int it = 0; it < 16; ++it) {
        int f4  = it * 256 + tid;
        int row = f4 >> 6, c4 = f4 & 63;
        int grow = row0 + row; if (grow >= L_NODES) grow = L_NODES - 1;
        float4 v = *(const float4*)(X + (size_t)grow * NFEAT + c4 * 4);
        bf16x4 o; o[0]=(__bf16)v.x; o[1]=(__bf16)v.y; o[2]=(__bf16)v.z; o[3]=(__bf16)v.w;
        *(bf16x4*)&Sm[row * 264 + c4 * 4] = o;
    }

    // b1 panel (phase-1 only, 64 regs): issue before the barrier so the L2
    // latency hides under the barrier wait.
    bf16x8 b1[2][8];
    #pragma unroll
    for (int nt = 0; nt < 2; ++nt) {
        int ntg = wave * 2 + nt;
        #pragma unroll
        for (int ks = 0; ks < 8; ++ks)
            b1[nt][ks] = *(const bf16x8*)(WtH + (size_t)(ntg * 16 + lm) * 256 + ks * 32 + lq * 8);
    }
    __syncthreads();

    // ---- phase 1: H = relu(X @ Wh + b) ----
    floatx4 acc1[4][2] = {};
    #pragma unroll
    for (int ks = 0; ks < 8; ++ks) {
        bf16x8 af[4];
        #pragma unroll
        for (int t = 0; t < 4; ++t)
            af[t] = *(const bf16x8*)&Sm[(t * 16 + lm) * 264 + ks * 32 + lq * 8];
        #pragma unroll
        for (int t = 0; t < 4; ++t)
            #pragma unroll
            for (int nt = 0; nt < 2; ++nt)
                acc1[t][nt] = __builtin_amdgcn_mfma_f32_16x16x32_bf16(
                    af[t], b1[nt][ks], acc1[t][nt], 0, 0, 0);
    }

    // Hs is a separate buffer: no barrier needed before writing it.
    #pragma unroll
    for (int nt = 0; nt < 2; ++nt) {
        int col = (wave * 2 + nt) * 16 + lm;
        float bias = b[col];
        #pragma unroll
        for (int t = 0; t < 4; ++t)
            #pragma unroll
            for (int p = 0; p < 4; ++p)
                Hs[(t * 16 + lq * 4 + p) * 136 + col] =
                    (__bf16)fmaxf(acc1[t][nt][p] + bias, 0.f);
    }
    __syncthreads();   // Hs visible; all As reads done -> Sm reusable as Os

    // ---- phase 2 (two nt-halves, 32+32 regs each): U|V = H @ Wg2 ----
    #pragma unroll
    for (int h = 0; h < 2; ++h) {
        bf16x8 b2h[2][4];
        #pragma unroll
        for (int nt = 0; nt < 2; ++nt) {
            int ntg = wave * 4 + h * 2 + nt;
            #pragma unroll
            for (int ks = 0; ks < 4; ++ks)
                b2h[nt][ks] = *(const bf16x8*)(WtG2 + (size_t)(ntg * 16 + lm) * 128 + ks * 32 + lq * 8);
        }
        floatx4 acc2[4][2] = {};
        #pragma unroll
        for (int ks = 0; ks < 4; ++ks) {
            bf16x8 af[4];
            #pragma unroll
            for (int t = 0; t < 4; ++t)
                af[t] = *(const bf16x8*)&Hs[(t * 16 + lm) * 136 + ks * 32 + lq * 8];
            #pragma unroll
            for (int t = 0; t < 4; ++t)
                #pragma unroll
                for (int nt = 0; nt < 2; ++nt)
                    acc2[t][nt] = __builtin_amdgcn_mfma_f32_16x16x32_bf16(
                        af[t], b2h[nt][ks], acc2[t][nt], 0, 0, 0);
        }
        // flush this half into Os (aliases As; As reads closed by the barrier)
        #pragma unroll
        for (int nt = 0; nt < 2; ++nt) {
            int col = (wave * 4 + h * 2 + nt) * 16 + lm;
            #pragma unroll
            for (int t = 0; t < 4; ++t)
                #pragma unroll
                for (int p = 0; p < 4; ++p)
                    Sm[(t * 16 + lq * 4 + p) * 264 + col] = (__bf16)acc2[t][nt][p];
        }
    }
    __syncthreads();

    // coalesced store of U|V from Os
    #pragma unroll
    for (int it = 0; it < 8; ++it) {
        int fid = it * 256 + tid;
        int row = fid >> 5, c8 = fid & 31;
        int grow = row0 + row;
        if (grow < L_NODES) {
            int col = c8 * 8;
            bf16x8 v = *(bf16x8*)&Sm[row * 264 + col];
            if (col < 128) *(bf16x8*)(U + (size_t)grow * JDIM + col) = v;
            else           *(bf16x8*)(V + (size_t)grow * JDIM + (col - 128)) = v;
        }
    }
}

// ---------------------------------------------------------------------------
// Kernel 2 (fused gather + final).  R13 version (now <77.5 us):
//   - part[] aliases sidx[]; __launch_bounds__(256,4); 2-deep pipelined
//     gather; b3 loaded after phase A.
// ---------------------------------------------------------------------------
__global__ __launch_bounds__(256, 4) void k_gfinal(
    const __bf16* __restrict__ U, const __bf16* __restrict__ V,
    const __bf16* __restrict__ WtGv, const float* __restrict__ bg,
    const float* __restrict__ Wf, const float* __restrict__ bf,
    const int* __restrict__ idx0, const int* __restrict__ idx1,
    float* __restrict__ out)
{
    __shared__ int    sidx[2][8][64];               // 4 KB; part[] aliases this
    __shared__ __bf16 E1s[64 * 136];                // 17.4 KB
    __shared__ __bf16 Us [64 * 136];                // 17.4 KB
    float (*part)[64][2] = (float (*)[64][2])&sidx[0][0][0];   // 2 KB alias

    const int tid  = threadIdx.x;
    const int row0 = blockIdx.x * 64;
    const int wave = tid >> 6, lane = tid & 63;
    const int lm = lane & 15, lq = lane >> 4;

    // stage indices (1024 ints, 4/thread) and U tile (4 bf16x8/thread)
    #pragma unroll
    for (int it = 0; it < 4; ++it) {
        int fid = it * 256 + tid;                 // 0..1023
        int m = fid >> 9, rem = fid & 511;
        int s = rem >> 6, il = rem & 63;
        int gr = row0 + il; if (gr >= L_NODES) gr = L_NODES - 1;
        sidx[m][s][il] = (m ? idx1 : idx0)[(size_t)s * L_NODES + gr];
    }
    #pragma unroll
    for (int it = 0; it < 4; ++it) {
        int fid = it * 256 + tid;                 // 0..1023
        int r = fid >> 4, c8 = fid & 15;
        int g = row0 + r; if (g >= L_NODES) g = L_NODES - 1;
        *(bf16x8*)&Us[r * 136 + c8 * 8] = *(const bf16x8*)(U + (size_t)g * JDIM + c8 * 8);
    }
    __syncthreads();

    // ---- phase A: gather-add into E1s (2-deep pipelined) ----
    {
        const int c0 = (tid & 15) * 8;            // col chunk
        const int rb = tid >> 4;                  // row base 0..15 (+16k)
        float bias[8];
        *(float4*)&bias[0] = *(const float4*)(bg + c0);
        *(float4*)&bias[4] = *(const float4*)(bg + c0 + 4);

        float acc[4][8] = {};
        bf16x8 uA[4], vA[4], uB[4], vB[4];

        auto LOADP = [&](int s, bf16x8 (&uu)[4], bf16x8 (&vv)[4]) {
            #pragma unroll
            for (int rr = 0; rr < 4; ++rr) {
                int r = rb + rr * 16;
                int a0 = sidx[0][s][r], a1 = sidx[1][s][r];
                uu[rr] = *(const bf16x8*)(U + (size_t)a0 * JDIM + c0);
                vv[rr] = *(const bf16x8*)(V + (size_t)a1 * JDIM + c0);
            }
        };
        auto ACCUM = [&](bf16x8 (&uu)[4], bf16x8 (&vv)[4]) {
            #pragma unroll
            for (int rr = 0; rr < 4; ++rr)
                #pragma unroll
                for (int p = 0; p < 8; ++p)
                    acc[rr][p] += fmaxf((float)uu[rr][p] + (float)vv[rr][p] + bias[p], 0.f);
        };

        LOADP(0, uA, vA);
        #pragma unroll
        for (int s = 0; s < 8; ++s) {
            if ((s & 1) == 0) {
                if (s < 7) LOADP(s + 1, uB, vB);
                ACCUM(uA, vA);
            } else {
                if (s < 7) LOADP(s + 1, uA, vA);
                ACCUM(uB, vB);
            }
        }

        #pragma unroll
        for (int rr = 0; rr < 4; ++rr) {
            int r = rb + rr * 16;
            bf16x8 o;
            #pragma unroll
            for (int p = 0; p < 8; ++p)
                o[p] = (__bf16)fmaxf(acc[rr][p] * 0.125f, 0.f);
            *(bf16x8*)&E1s[r * 136 + c0] = o;
        }
    }
    __syncthreads();   // also closes all sidx reads before part[] writes

    // B panel (phase-B-only): load now so it doesn't hold VGPRs in phase A
    bf16x8 b3[2][4];
    #pragma unroll
    for (int nt = 0; nt < 2; ++nt) {
        int ntg = wave * 2 + nt;
        #pragma unroll
        for (int ks = 0; ks < 4; ++ks)
            b3[nt][ks] = *(const bf16x8*)(WtGv + (size_t)(ntg * 16 + lm) * 128 + ks * 32 + lq * 8);
    }

    // ---- phase B: E2 = relu(U + E1 @ Wg_bot + bg); head ----
    floatx4 acc[4][2] = {};
    #pragma unroll
    for (int ks = 0; ks < 4; ++ks) {
        bf16x8 af[4];
        #pragma unroll
        for (int t = 0; t < 4; ++t)
            af[t] = *(const bf16x8*)&E1s[(t * 16 + lm) * 136 + ks * 32 + lq * 8];
        #pragma unroll
        for (int t = 0; t < 4; ++t)
            #pragma unroll
            for (int nt = 0; nt < 2; ++nt)
                acc[t][nt] = __builtin_amdgcn_mfma_f32_16x16x32_bf16(
                    af[t], b3[nt][ks], acc[t][nt], 0, 0, 0);
    }

    float bias[2], wf0[2], wf1[2];
    #pragma unroll
    for (int nt = 0; nt < 2; ++nt) {
        int col = (wave * 2 + nt) * 16 + lm;
        bias[nt] = bg[col];
        wf0[nt] = Wf[col * 2 + 0];
        wf1[nt] = Wf[col * 2 + 1];
    }
    #pragma unroll
    for (int t = 0; t < 4; ++t) {
        float p0[4], p1[4];
        #pragma unroll
        for (int p = 0; p < 4; ++p) {
            int r = t * 16 + lq * 4 + p;
            float a0 = 0.f, a1 = 0.f;
            #pragma unroll
            for (int nt = 0; nt < 2; ++nt) {
                int col = (wave * 2 + nt) * 16 + lm;
                float e2 = fmaxf((float)Us[r * 136 + col] + acc[t][nt][p] + bias[nt], 0.f);
                a0 = fmaf(e2, wf0[nt], a0);
                a1 = fmaf(e2, wf1[nt], a1);
            }
            p0[p] = a0; p1[p] = a1;
        }
        #pragma unroll
        for (int m = 1; m <= 8; m <<= 1)
            #pragma unroll
            for (int p = 0; p < 4; ++p) {
                p0[p] += __shfl_xor(p0[p], m, 16);
                p1[p] += __shfl_xor(p1[p], m, 16);
            }
        if (lm == 0)
            #pragma unroll
            for (int p = 0; p < 4; ++p) {
                part[wave][t * 16 + lq * 4 + p][0] = p0[p];
                part[wave][t * 16 + lq * 4 + p][1] = p1[p];
            }
    }
    __syncthreads();

    if (tid < 128) {
        int row = tid >> 1, o = tid & 1;
        int grow = row0 + row;
        if (grow < L_NODES)
            out[(size_t)grow * 2 + o] =
                part[0][row][o] + part[1][row][o] + part[2][row][o] + part[3][row][o] + bf[o];
    }
}

// ---------------------------------------------------------------------------
extern "C" void kernel_launch(void* const* d_in, const int* in_sizes, int n_in,
                              void* d_out, int out_size, void* d_ws, size_t ws_size,
                              hipStream_t stream) {
    const float* X    = (const float*)d_in[0];
    const float* W_h1 = (const float*)d_in[1];
    const float* b_h1 = (const float*)d_in[2];
    const float* W_g1 = (const float*)d_in[3];
    const float* b_g1 = (const float*)d_in[4];
    const float* W_f  = (const float*)d_in[5];
    const float* b_f  = (const float*)d_in[6];
    const int*   idx0 = (const int*)d_in[7];
    const int*   idx1 = (const int*)d_in[8];
    float* out = (float*)d_out;

    __bf16* U    = (__bf16*)d_ws;                         // 25.6 MB
    __bf16* V    = U   + (size_t)L_NODES * JDIM;          // 25.6 MB
    __bf16* WtH  = V   + (size_t)L_NODES * JDIM;          // 64 KB
    __bf16* WtG2 = WtH + 32768;                           // 64 KB
    __bf16* WtGv = WtG2 + 128 * 128;                      // alias: rows 128.. of WtG2

    k_prep<<<128, 256, 0, stream>>>(W_h1, W_g1, WtH, WtG2);
    k_h1uv<<<(L_NODES + 63) / 64, 256, 0, stream>>>(X, WtH, WtG2, b_h1, U, V);
    k_gfinal<<<(L_NODES + 63) / 64, 256, 0, stream>>>(U, V, WtGv, b_g1, W_f, b_f,
                                                      idx0, idx1, out);
}

// Round 4
// 253.170 us; speedup vs baseline: 1.0607x; 1.0203x over previous
//
#include <hip/hip_runtime.h>

#define L_NODES 100000
#define NFEAT   256
#define JDIM    128

typedef __bf16 bf16x8 __attribute__((ext_vector_type(8)));
typedef __bf16 bf16x4 __attribute__((ext_vector_type(4)));
typedef float  floatx4 __attribute__((ext_vector_type(4)));

// ---------------------------------------------------------------------------
// Prep:
//   WtH [128][256]: WtH[n][k]  = bf16(W_h1[k][n])
//   WtG2[256][128]: n<128: Wg[k][n]   (U cols);  n>=128: Wg[128+k][n-128] (V cols)
//     rows 128.. of WtG2 double as WtGv[n][k]=Wg[128+k][n] for k_gfinal.
// ---------------------------------------------------------------------------
__global__ __launch_bounds__(256) void k_prep(
    const float* __restrict__ Wh, const float* __restrict__ Wg,
    __bf16* __restrict__ WtH, __bf16* __restrict__ WtG2)
{
    int i = blockIdx.x * 256 + threadIdx.x;   // 32768
    int n = i >> 8, k = i & 255;
    WtH[i] = (__bf16)Wh[k * JDIM + n];
    int n2 = i >> 7, k2 = i & 127;
    WtG2[i] = (n2 < 128) ? (__bf16)Wg[k2 * JDIM + n2]
                         : (__bf16)Wg[(128 + k2) * JDIM + (n2 - 128)];
}

// ---------------------------------------------------------------------------
// Kernel 1 (fused h1+uv).  R15: the staging loop's load->cvt->ds_write
// interleave let the compiler chunk the 16 HBM loads into small groups with
// a vmcnt wait per group (~4-8 exposed latencies per block).  Split into
// two passes over an explicit float4 xa[16] register array (static indexing)
// so all 16 loads are in flight before the first consume -> ONE exposure.
// Rest of the R14 structure (3 barriers, phase-2 split, separate Hs) kept.
// ---------------------------------------------------------------------------
__global__ __launch_bounds__(256, 3) void k_h1uv(
    const float* __restrict__ X, const __bf16* __restrict__ WtH,
    const __bf16* __restrict__ WtG2, const float* __restrict__ b,
    __bf16* __restrict__ U, __bf16* __restrict__ V)
{
    __shared__ __bf16 Sm[64 * 264];   // X tile (As); later output restage (Os)
    __shared__ __bf16 Hs[64 * 136];   // H activations

    const int tid  = threadIdx.x;
    const int row0 = blockIdx.x * 64;
    const int wave = tid >> 6, lane = tid & 63;
    const int lm = lane & 15, lq = lane >> 4;

    // ---- stage X tile: pass 1 = issue ALL 16 loads; pass 2 = cvt + write ----
    float4 xa[16];
    #pragma unroll
    for (int it = 0; it < 16; ++it) {
        int f4  = it * 256 + tid;
        int row = f4 >> 6, c4 = f4 & 63;
        int grow = row0 + row; if (grow >= L_NODES) grow = L_NODES - 1;
        xa[it] = *(const float4*)(X + (size_t)grow * NFEAT + c4 * 4);
    }
    #pragma unroll
    for (int it = 0; it < 16; ++it) {
        int f4  = it * 256 + tid;
        int row = f4 >> 6, c4 = f4 & 63;
        bf16x4 o;
        o[0]=(__bf16)xa[it].x; o[1]=(__bf16)xa[it].y;
        o[2]=(__bf16)xa[it].z; o[3]=(__bf16)xa[it].w;
        *(bf16x4*)&Sm[row * 264 + c4 * 4] = o;
    }

    // b1 panel (phase-1 only): xa is dead now, so these 16 loads batch freely;
    // their latency hides under the barrier wait.
    bf16x8 b1[2][8];
    #pragma unroll
    for (int nt = 0; nt < 2; ++nt) {
        int ntg = wave * 2 + nt;
        #pragma unroll
        for (int ks = 0; ks < 8; ++ks)
            b1[nt][ks] = *(const bf16x8*)(WtH + (size_t)(ntg * 16 + lm) * 256 + ks * 32 + lq * 8);
    }
    __syncthreads();

    // ---- phase 1: H = relu(X @ Wh + b) ----
    floatx4 acc1[4][2] = {};
    #pragma unroll
    for (int ks = 0; ks < 8; ++ks) {
        bf16x8 af[4];
        #pragma unroll
        for (int t = 0; t < 4; ++t)
            af[t] = *(const bf16x8*)&Sm[(t * 16 + lm) * 264 + ks * 32 + lq * 8];
        #pragma unroll
        for (int t = 0; t < 4; ++t)
            #pragma unroll
            for (int nt = 0; nt < 2; ++nt)
                acc1[t][nt] = __builtin_amdgcn_mfma_f32_16x16x32_bf16(
                    af[t], b1[nt][ks], acc1[t][nt], 0, 0, 0);
    }

    // Hs is a separate buffer: no barrier needed before writing it.
    #pragma unroll
    for (int nt = 0; nt < 2; ++nt) {
        int col = (wave * 2 + nt) * 16 + lm;
        float bias = b[col];
        #pragma unroll
        for (int t = 0; t < 4; ++t)
            #pragma unroll
            for (int p = 0; p < 4; ++p)
                Hs[(t * 16 + lq * 4 + p) * 136 + col] =
                    (__bf16)fmaxf(acc1[t][nt][p] + bias, 0.f);
    }
    __syncthreads();   // Hs visible; all As reads done -> Sm reusable as Os

    // ---- phase 2 (two nt-halves, JIT weight panels): U|V = H @ Wg2 ----
    #pragma unroll
    for (int h = 0; h < 2; ++h) {
        bf16x8 b2h[2][4];
        #pragma unroll
        for (int nt = 0; nt < 2; ++nt) {
            int ntg = wave * 4 + h * 2 + nt;
            #pragma unroll
            for (int ks = 0; ks < 4; ++ks)
                b2h[nt][ks] = *(const bf16x8*)(WtG2 + (size_t)(ntg * 16 + lm) * 128 + ks * 32 + lq * 8);
        }
        floatx4 acc2[4][2] = {};
        #pragma unroll
        for (int ks = 0; ks < 4; ++ks) {
            bf16x8 af[4];
            #pragma unroll
            for (int t = 0; t < 4; ++t)
                af[t] = *(const bf16x8*)&Hs[(t * 16 + lm) * 136 + ks * 32 + lq * 8];
            #pragma unroll
            for (int t = 0; t < 4; ++t)
                #pragma unroll
                for (int nt = 0; nt < 2; ++nt)
                    acc2[t][nt] = __builtin_amdgcn_mfma_f32_16x16x32_bf16(
                        af[t], b2h[nt][ks], acc2[t][nt], 0, 0, 0);
        }
        // flush this half into Os (aliases As; As reads closed by the barrier)
        #pragma unroll
        for (int nt = 0; nt < 2; ++nt) {
            int col = (wave * 4 + h * 2 + nt) * 16 + lm;
            #pragma unroll
            for (int t = 0; t < 4; ++t)
                #pragma unroll
                for (int p = 0; p < 4; ++p)
                    Sm[(t * 16 + lq * 4 + p) * 264 + col] = (__bf16)acc2[t][nt][p];
        }
    }
    __syncthreads();

    // coalesced store of U|V from Os
    #pragma unroll
    for (int it = 0; it < 8; ++it) {
        int fid = it * 256 + tid;
        int row = fid >> 5, c8 = fid & 31;
        int grow = row0 + row;
        if (grow < L_NODES) {
            int col = c8 * 8;
            bf16x8 v = *(bf16x8*)&Sm[row * 264 + col];
            if (col < 128) *(bf16x8*)(U + (size_t)grow * JDIM + col) = v;
            else           *(bf16x8*)(V + (size_t)grow * JDIM + (col - 128)) = v;
        }
    }
}

// ---------------------------------------------------------------------------
// Kernel 2 (fused gather + final).  Unchanged from R13 (67.5 us, 3.0 TB/s on
// random 256B gathers; in-flight-bytes arithmetic says MLP is not the
// limiter, so no register-pressure risk taken here).
// ---------------------------------------------------------------------------
__global__ __launch_bounds__(256, 4) void k_gfinal(
    const __bf16* __restrict__ U, const __bf16* __restrict__ V,
    const __bf16* __restrict__ WtGv, const float* __restrict__ bg,
    const float* __restrict__ Wf, const float* __restrict__ bf,
    const int* __restrict__ idx0, const int* __restrict__ idx1,
    float* __restrict__ out)
{
    __shared__ int    sidx[2][8][64];               // 4 KB; part[] aliases this
    __shared__ __bf16 E1s[64 * 136];                // 17.4 KB
    __shared__ __bf16 Us [64 * 136];                // 17.4 KB
    float (*part)[64][2] = (float (*)[64][2])&sidx[0][0][0];   // 2 KB alias

    const int tid  = threadIdx.x;
    const int row0 = blockIdx.x * 64;
    const int wave = tid >> 6, lane = tid & 63;
    const int lm = lane & 15, lq = lane >> 4;

    // stage indices (1024 ints, 4/thread) and U tile (4 bf16x8/thread)
    #pragma unroll
    for (int it = 0; it < 4; ++it) {
        int fid = it * 256 + tid;                 // 0..1023
        int m = fid >> 9, rem = fid & 511;
        int s = rem >> 6, il = rem & 63;
        int gr = row0 + il; if (gr >= L_NODES) gr = L_NODES - 1;
        sidx[m][s][il] = (m ? idx1 : idx0)[(size_t)s * L_NODES + gr];
    }
    #pragma unroll
    for (int it = 0; it < 4; ++it) {
        int fid = it * 256 + tid;                 // 0..1023
        int r = fid >> 4, c8 = fid & 15;
        int g = row0 + r; if (g >= L_NODES) g = L_NODES - 1;
        *(bf16x8*)&Us[r * 136 + c8 * 8] = *(const bf16x8*)(U + (size_t)g * JDIM + c8 * 8);
    }
    __syncthreads();

    // ---- phase A: gather-add into E1s (2-deep pipelined) ----
    {
        const int c0 = (tid & 15) * 8;            // col chunk
        const int rb = tid >> 4;                  // row base 0..15 (+16k)
        float bias[8];
        *(float4*)&bias[0] = *(const float4*)(bg + c0);
        *(float4*)&bias[4] = *(const float4*)(bg + c0 + 4);

        float acc[4][8] = {};
        bf16x8 uA[4], vA[4], uB[4], vB[4];

        auto LOADP = [&](int s, bf16x8 (&uu)[4], bf16x8 (&vv)[4]) {
            #pragma unroll
            for (int rr = 0; rr < 4; ++rr) {
                int r = rb + rr * 16;
                int a0 = sidx[0][s][r], a1 = sidx[1][s][r];
                uu[rr] = *(const bf16x8*)(U + (size_t)a0 * JDIM + c0);
                vv[rr] = *(const bf16x8*)(V + (size_t)a1 * JDIM + c0);
            }
        };
        auto ACCUM = [&](bf16x8 (&uu)[4], bf16x8 (&vv)[4]) {
            #pragma unroll
            for (int rr = 0; rr < 4; ++rr)
                #pragma unroll
                for (int p = 0; p < 8; ++p)
                    acc[rr][p] += fmaxf((float)uu[rr][p] + (float)vv[rr][p] + bias[p], 0.f);
        };

        LOADP(0, uA, vA);
        #pragma unroll
        for (int s = 0; s < 8; ++s) {
            if ((s & 1) == 0) {
                if (s < 7) LOADP(s + 1, uB, vB);
                ACCUM(uA, vA);
            } else {
                if (s < 7) LOADP(s + 1, uA, vA);
                ACCUM(uB, vB);
            }
        }

        #pragma unroll
        for (int rr = 0; rr < 4; ++rr) {
            int r = rb + rr * 16;
            bf16x8 o;
            #pragma unroll
            for (int p = 0; p < 8; ++p)
                o[p] = (__bf16)fmaxf(acc[rr][p] * 0.125f, 0.f);
            *(bf16x8*)&E1s[r * 136 + c0] = o;
        }
    }
    __syncthreads();   // also closes all sidx reads before part[] writes

    // B panel (phase-B-only): load now so it doesn't hold VGPRs in phase A
    bf16x8 b3[2][4];
    #pragma unroll
    for (int nt = 0; nt < 2; ++nt) {
        int ntg = wave * 2 + nt;
        #pragma unroll
        for (int ks = 0; ks < 4; ++ks)
            b3[nt][ks] = *(const bf16x8*)(WtGv + (size_t)(ntg * 16 + lm) * 128 + ks * 32 + lq * 8);
    }

    // ---- phase B: E2 = relu(U + E1 @ Wg_bot + bg); head ----
    floatx4 acc[4][2] = {};
    #pragma unroll
    for (int ks = 0; ks < 4; ++ks) {
        bf16x8 af[4];
        #pragma unroll
        for (int t = 0; t < 4; ++t)
            af[t] = *(const bf16x8*)&E1s[(t * 16 + lm) * 136 + ks * 32 + lq * 8];
        #pragma unroll
        for (int t = 0; t < 4; ++t)
            #pragma unroll
            for (int nt = 0; nt < 2; ++nt)
                acc[t][nt] = __builtin_amdgcn_mfma_f32_16x16x32_bf16(
                    af[t], b3[nt][ks], acc[t][nt], 0, 0, 0);
    }

    float bias[2], wf0[2], wf1[2];
    #pragma unroll
    for (int nt = 0; nt < 2; ++nt) {
        int col = (wave * 2 + nt) * 16 + lm;
        bias[nt] = bg[col];
        wf0[nt] = Wf[col * 2 + 0];
        wf1[nt] = Wf[col * 2 + 1];
    }
    #pragma unroll
    for (int t = 0; t < 4; ++t) {
        float p0[4], p1[4];
        #pragma unroll
        for (int p = 0; p < 4; ++p) {
            int r = t * 16 + lq * 4 + p;
            float a0 = 0.f, a1 = 0.f;
            #pragma unroll
            for (int nt = 0; nt < 2; ++nt) {
                int col = (wave * 2 + nt) * 16 + lm;
                float e2 = fmaxf((float)Us[r * 136 + col] + acc[t][nt][p] + bias[nt], 0.f);
                a0 = fmaf(e2, wf0[nt], a0);
                a1 = fmaf(e2, wf1[nt], a1);
            }
            p0[p] = a0; p1[p] = a1;
        }
        #pragma unroll
        for (int m = 1; m <= 8; m <<= 1)
            #pragma unroll
            for (int p = 0; p < 4; ++p) {
                p0[p] += __shfl_xor(p0[p], m, 16);
                p1[p] += __shfl_xor(p1[p], m, 16);
            }
        if (lm == 0)
            #pragma unroll
            for (int p = 0; p < 4; ++p) {
                part[wave][t * 16 + lq * 4 + p][0] = p0[p];
                part[wave][t * 16 + lq * 4 + p][1] = p1[p];
            }
    }
    __syncthreads();

    if (tid < 128) {
        int row = tid >> 1, o = tid & 1;
        int grow = row0 + row;
        if (grow < L_NODES)
            out[(size_t)grow * 2 + o] =
                part[0][row][o] + part[1][row][o] + part[2][row][o] + part[3][row][o] + bf[o];
    }
}

// ---------------------------------------------------------------------------
extern "C" void kernel_launch(void* const* d_in, const int* in_sizes, int n_in,
                              void* d_out, int out_size, void* d_ws, size_t ws_size,
                              hipStream_t stream) {
    const float* X    = (const float*)d_in[0];
    const float* W_h1 = (const float*)d_in[1];
    const float* b_h1 = (const float*)d_in[2];
    const float* W_g1 = (const float*)d_in[3];
    const float* b_g1 = (const float*)d_in[4];
    const float* W_f  = (const float*)d_in[5];
    const float* b_f  = (const float*)d_in[6];
    const int*   idx0 = (const int*)d_in[7];
    const int*   idx1 = (const int*)d_in[8];
    float* out = (float*)d_out;

    __bf16* U    = (__bf16*)d_ws;                         // 25.6 MB
    __bf16* V    = U   + (size_t)L_NODES * JDIM;          // 25.6 MB
    __bf16* WtH  = V   + (size_t)L_NODES * JDIM;          // 64 KB
    __bf16* WtG2 = WtH + 32768;                           // 64 KB
    __bf16* WtGv = WtG2 + 128 * 128;                      // alias: rows 128.. of WtG2

    k_prep<<<128, 256, 0, stream>>>(W_h1, W_g1, WtH, WtG2);
    k_h1uv<<<(L_NODES + 63) / 64, 256, 0, stream>>>(X, WtH, WtG2, b_h1, U, V);
    k_gfinal<<<(L_NODES + 63) / 64, 256, 0, stream>>>(U, V, WtGv, b_g1, W_f, b_f,
                                                      idx0, idx1, out);
}

// Round 7
// 249.738 us; speedup vs baseline: 1.0752x; 1.0137x over previous
//
#include <hip/hip_runtime.h>

#define L_NODES 100000
#define NFEAT   256
#define JDIM    128

typedef __bf16 bf16x8 __attribute__((ext_vector_type(8)));
typedef __bf16 bf16x4 __attribute__((ext_vector_type(4)));
typedef float  floatx4 __attribute__((ext_vector_type(4)));

// ---------------------------------------------------------------------------
// Prep:
//   WtH [128][256]: WtH[n][k]  = bf16(W_h1[k][n])
//   WtG2[256][128]: n<128: Wg[k][n]   (U cols);  n>=128: Wg[128+k][n-128] (V cols)
//     rows 128.. of WtG2 double as WtGv[n][k]=Wg[128+k][n] for k_gfinal.
// ---------------------------------------------------------------------------
__global__ __launch_bounds__(256) void k_prep(
    const float* __restrict__ Wh, const float* __restrict__ Wg,
    __bf16* __restrict__ WtH, __bf16* __restrict__ WtG2)
{
    int i = blockIdx.x * 256 + threadIdx.x;   // 32768
    int n = i >> 8, k = i & 255;
    WtH[i] = (__bf16)Wh[k * JDIM + n];
    int n2 = i >> 7, k2 = i & 127;
    WtG2[i] = (n2 < 128) ? (__bf16)Wg[k2 * JDIM + n2]
                         : (__bf16)Wg[(128 + k2) * JDIM + (n2 - 128)];
}

// ---------------------------------------------------------------------------
// Kernel 1 (fused h1+uv).  R18 == R16 with the NT load through an
// ext_vector_type float4 (Clang vector; HIP_vector_type float4 is a class
// and rejected by __builtin_nontemporal_load).  Theory: X (102.4 MB,
// read-once-streaming) occupies ~half the 256MB L3 and evicts the U/V lines
// k_gfinal's random gather re-reads 8x; NT steers L3 budget to U/V.
// ---------------------------------------------------------------------------
__global__ __launch_bounds__(256, 3) void k_h1uv(
    const float* __restrict__ X, const __bf16* __restrict__ WtH,
    const __bf16* __restrict__ WtG2, const float* __restrict__ b,
    __bf16* __restrict__ U, __bf16* __restrict__ V)
{
    __shared__ __bf16 Sm[64 * 264];   // X tile (As); later output restage (Os)
    __shared__ __bf16 Hs[64 * 136];   // H activations

    const int tid  = threadIdx.x;
    const int row0 = blockIdx.x * 64;
    const int wave = tid >> 6, lane = tid & 63;
    const int lm = lane & 15, lq = lane >> 4;

    // ---- stage X tile: pass 1 = issue ALL 16 loads (NT); pass 2 = cvt+write --
    floatx4 xa[16];
    #pragma unroll
    for (int it = 0; it < 16; ++it) {
        int f4  = it * 256 + tid;
        int row = f4 >> 6, c4 = f4 & 63;
        int grow = row0 + row; if (grow >= L_NODES) grow = L_NODES - 1;
        xa[it] = __builtin_nontemporal_load(
                     reinterpret_cast<const floatx4*>(X + (size_t)grow * NFEAT + c4 * 4));
    }
    #pragma unroll
    for (int it = 0; it < 16; ++it) {
        int f4  = it * 256 + tid;
        int row = f4 >> 6, c4 = f4 & 63;
        bf16x4 o;
        o[0]=(__bf16)xa[it][0]; o[1]=(__bf16)xa[it][1];
        o[2]=(__bf16)xa[it][2]; o[3]=(__bf16)xa[it][3];
        *(bf16x4*)&Sm[row * 264 + c4 * 4] = o;
    }

    // b1 panel (phase-1 only): xa dead now; latency hides under the barrier.
    bf16x8 b1[2][8];
    #pragma unroll
    for (int nt = 0; nt < 2; ++nt) {
        int ntg = wave * 2 + nt;
        #pragma unroll
        for (int ks = 0; ks < 8; ++ks)
            b1[nt][ks] = *(const bf16x8*)(WtH + (size_t)(ntg * 16 + lm) * 256 + ks * 32 + lq * 8);
    }
    __syncthreads();

    // ---- phase 1: H = relu(X @ Wh + b) ----
    floatx4 acc1[4][2] = {};
    #pragma unroll
    for (int ks = 0; ks < 8; ++ks) {
        bf16x8 af[4];
        #pragma unroll
        for (int t = 0; t < 4; ++t)
            af[t] = *(const bf16x8*)&Sm[(t * 16 + lm) * 264 + ks * 32 + lq * 8];
        #pragma unroll
        for (int t = 0; t < 4; ++t)
            #pragma unroll
            for (int nt = 0; nt < 2; ++nt)
                acc1[t][nt] = __builtin_amdgcn_mfma_f32_16x16x32_bf16(
                    af[t], b1[nt][ks], acc1[t][nt], 0, 0, 0);
    }

    // Hs is a separate buffer: no barrier needed before writing it.
    #pragma unroll
    for (int nt = 0; nt < 2; ++nt) {
        int col = (wave * 2 + nt) * 16 + lm;
        float bias = b[col];
        #pragma unroll
        for (int t = 0; t < 4; ++t)
            #pragma unroll
            for (int p = 0; p < 4; ++p)
                Hs[(t * 16 + lq * 4 + p) * 136 + col] =
                    (__bf16)fmaxf(acc1[t][nt][p] + bias, 0.f);
    }
    __syncthreads();   // Hs visible; all As reads done -> Sm reusable as Os

    // ---- phase 2 (two nt-halves, JIT weight panels): U|V = H @ Wg2 ----
    #pragma unroll
    for (int h = 0; h < 2; ++h) {
        bf16x8 b2h[2][4];
        #pragma unroll
        for (int nt = 0; nt < 2; ++nt) {
            int ntg = wave * 4 + h * 2 + nt;
            #pragma unroll
            for (int ks = 0; ks < 4; ++ks)
                b2h[nt][ks] = *(const bf16x8*)(WtG2 + (size_t)(ntg * 16 + lm) * 128 + ks * 32 + lq * 8);
        }
        floatx4 acc2[4][2] = {};
        #pragma unroll
        for (int ks = 0; ks < 4; ++ks) {
            bf16x8 af[4];
            #pragma unroll
            for (int t = 0; t < 4; ++t)
                af[t] = *(const bf16x8*)&Hs[(t * 16 + lm) * 136 + ks * 32 + lq * 8];
            #pragma unroll
            for (int t = 0; t < 4; ++t)
                #pragma unroll
                for (int nt = 0; nt < 2; ++nt)
                    acc2[t][nt] = __builtin_amdgcn_mfma_f32_16x16x32_bf16(
                        af[t], b2h[nt][ks], acc2[t][nt], 0, 0, 0);
        }
        // flush this half into Os (aliases As; As reads closed by the barrier)
        #pragma unroll
        for (int nt = 0; nt < 2; ++nt) {
            int col = (wave * 4 + h * 2 + nt) * 16 + lm;
            #pragma unroll
            for (int t = 0; t < 4; ++t)
                #pragma unroll
                for (int p = 0; p < 4; ++p)
                    Sm[(t * 16 + lq * 4 + p) * 264 + col] = (__bf16)acc2[t][nt][p];
        }
    }
    __syncthreads();

    // coalesced store of U|V from Os (default-cached: gathers re-read these)
    #pragma unroll
    for (int it = 0; it < 8; ++it) {
        int fid = it * 256 + tid;
        int row = fid >> 5, c8 = fid & 31;
        int grow = row0 + row;
        if (grow < L_NODES) {
            int col = c8 * 8;
            bf16x8 v = *(bf16x8*)&Sm[row * 264 + col];
            if (col < 128) *(bf16x8*)(U + (size_t)grow * JDIM + col) = v;
            else           *(bf16x8*)(V + (size_t)grow * JDIM + (col - 128)) = v;
        }
    }
}

// ---------------------------------------------------------------------------
// Kernel 2 (fused gather + final).  R18 == R16: idx loads NT (6.4 MB
// single-use stream), out store NT (single-use).  Gather loads stay
// default-cached — they're the L3 beneficiary.  Structure unchanged.
// ---------------------------------------------------------------------------
__global__ __launch_bounds__(256, 4) void k_gfinal(
    const __bf16* __restrict__ U, const __bf16* __restrict__ V,
    const __bf16* __restrict__ WtGv, const float* __restrict__ bg,
    const float* __restrict__ Wf, const float* __restrict__ bf,
    const int* __restrict__ idx0, const int* __restrict__ idx1,
    float* __restrict__ out)
{
    __shared__ int    sidx[2][8][64];               // 4 KB; part[] aliases this
    __shared__ __bf16 E1s[64 * 136];                // 17.4 KB
    __shared__ __bf16 Us [64 * 136];                // 17.4 KB
    float (*part)[64][2] = (float (*)[64][2])&sidx[0][0][0];   // 2 KB alias

    const int tid  = threadIdx.x;
    const int row0 = blockIdx.x * 64;
    const int wave = tid >> 6, lane = tid & 63;
    const int lm = lane & 15, lq = lane >> 4;

    // stage indices (1024 ints, 4/thread, NT) and U tile (4 bf16x8/thread)
    #pragma unroll
    for (int it = 0; it < 4; ++it) {
        int fid = it * 256 + tid;                 // 0..1023
        int m = fid >> 9, rem = fid & 511;
        int s = rem >> 6, il = rem & 63;
        int gr = row0 + il; if (gr >= L_NODES) gr = L_NODES - 1;
        const int* ip = (m ? idx1 : idx0) + (size_t)s * L_NODES + gr;
        sidx[m][s][il] = __builtin_nontemporal_load(ip);
    }
    #pragma unroll
    for (int it = 0; it < 4; ++it) {
        int fid = it * 256 + tid;                 // 0..1023
        int r = fid >> 4, c8 = fid & 15;
        int g = row0 + r; if (g >= L_NODES) g = L_NODES - 1;
        *(bf16x8*)&Us[r * 136 + c8 * 8] = *(const bf16x8*)(U + (size_t)g * JDIM + c8 * 8);
    }
    __syncthreads();

    // ---- phase A: gather-add into E1s (2-deep pipelined) ----
    {
        const int c0 = (tid & 15) * 8;            // col chunk
        const int rb = tid >> 4;                  // row base 0..15 (+16k)
        float bias[8];
        *(float4*)&bias[0] = *(const float4*)(bg + c0);
        *(float4*)&bias[4] = *(const float4*)(bg + c0 + 4);

        float acc[4][8] = {};
        bf16x8 uA[4], vA[4], uB[4], vB[4];

        auto LOADP = [&](int s, bf16x8 (&uu)[4], bf16x8 (&vv)[4]) {
            #pragma unroll
            for (int rr = 0; rr < 4; ++rr) {
                int r = rb + rr * 16;
                int a0 = sidx[0][s][r], a1 = sidx[1][s][r];
                uu[rr] = *(const bf16x8*)(U + (size_t)a0 * JDIM + c0);
                vv[rr] = *(const bf16x8*)(V + (size_t)a1 * JDIM + c0);
            }
        };
        auto ACCUM = [&](bf16x8 (&uu)[4], bf16x8 (&vv)[4]) {
            #pragma unroll
            for (int rr = 0; rr < 4; ++rr)
                #pragma unroll
                for (int p = 0; p < 8; ++p)
                    acc[rr][p] += fmaxf((float)uu[rr][p] + (float)vv[rr][p] + bias[p], 0.f);
        };

        LOADP(0, uA, vA);
        #pragma unroll
        for (int s = 0; s < 8; ++s) {
            if ((s & 1) == 0) {
                if (s < 7) LOADP(s + 1, uB, vB);
                ACCUM(uA, vA);
            } else {
                if (s < 7) LOADP(s + 1, uA, vA);
                ACCUM(uB, vB);
            }
        }

        #pragma unroll
        for (int rr = 0; rr < 4; ++rr) {
            int r = rb + rr * 16;
            bf16x8 o;
            #pragma unroll
            for (int p = 0; p < 8; ++p)
                o[p] = (__bf16)fmaxf(acc[rr][p] * 0.125f, 0.f);
            *(bf16x8*)&E1s[r * 136 + c0] = o;
        }
    }
    __syncthreads();   // also closes all sidx reads before part[] writes

    // B panel (phase-B-only): load now so it doesn't hold VGPRs in phase A
    bf16x8 b3[2][4];
    #pragma unroll
    for (int nt = 0; nt < 2; ++nt) {
        int ntg = wave * 2 + nt;
        #pragma unroll
        for (int ks = 0; ks < 4; ++ks)
            b3[nt][ks] = *(const bf16x8*)(WtGv + (size_t)(ntg * 16 + lm) * 128 + ks * 32 + lq * 8);
    }

    // ---- phase B: E2 = relu(U + E1 @ Wg_bot + bg); head ----
    floatx4 acc[4][2] = {};
    #pragma unroll
    for (int ks = 0; ks < 4; ++ks) {
        bf16x8 af[4];
        #pragma unroll
        for (int t = 0; t < 4; ++t)
            af[t] = *(const bf16x8*)&E1s[(t * 16 + lm) * 136 + ks * 32 + lq * 8];
        #pragma unroll
        for (int t = 0; t < 4; ++t)
            #pragma unroll
            for (int nt = 0; nt < 2; ++nt)
                acc[t][nt] = __builtin_amdgcn_mfma_f32_16x16x32_bf16(
                    af[t], b3[nt][ks], acc[t][nt], 0, 0, 0);
    }

    float bias[2], wf0[2], wf1[2];
    #pragma unroll
    for (int nt = 0; nt < 2; ++nt) {
        int col = (wave * 2 + nt) * 16 + lm;
        bias[nt] = bg[col];
        wf0[nt] = Wf[col * 2 + 0];
        wf1[nt] = Wf[col * 2 + 1];
    }
    #pragma unroll
    for (int t = 0; t < 4; ++t) {
        float p0[4], p1[4];
        #pragma unroll
        for (int p = 0; p < 4; ++p) {
            int r = t * 16 + lq * 4 + p;
            float a0 = 0.f, a1 = 0.f;
            #pragma unroll
            for (int nt = 0; nt < 2; ++nt) {
                int col = (wave * 2 + nt) * 16 + lm;
                float e2 = fmaxf((float)Us[r * 136 + col] + acc[t][nt][p] + bias[nt], 0.f);
                a0 = fmaf(e2, wf0[nt], a0);
                a1 = fmaf(e2, wf1[nt], a1);
            }
            p0[p] = a0; p1[p] = a1;
        }
        #pragma unroll
        for (int m = 1; m <= 8; m <<= 1)
            #pragma unroll
            for (int p = 0; p < 4; ++p) {
                p0[p] += __shfl_xor(p0[p], m, 16);
                p1[p] += __shfl_xor(p1[p], m, 16);
            }
        if (lm == 0)
            #pragma unroll
            for (int p = 0; p < 4; ++p) {
                part[wave][t * 16 + lq * 4 + p][0] = p0[p];
                part[wave][t * 16 + lq * 4 + p][1] = p1[p];
            }
    }
    __syncthreads();

    if (tid < 128) {
        int row = tid >> 1, o = tid & 1;
        int grow = row0 + row;
        if (grow < L_NODES) {
            float v = part[0][row][o] + part[1][row][o] + part[2][row][o]
                    + part[3][row][o] + bf[o];
            __builtin_nontemporal_store(v, &out[(size_t)grow * 2 + o]);
        }
    }
}

// ---------------------------------------------------------------------------
extern "C" void kernel_launch(void* const* d_in, const int* in_sizes, int n_in,
                              void* d_out, int out_size, void* d_ws, size_t ws_size,
                              hipStream_t stream) {
    const float* X    = (const float*)d_in[0];
    const float* W_h1 = (const float*)d_in[1];
    const float* b_h1 = (const float*)d_in[2];
    const float* W_g1 = (const float*)d_in[3];
    const float* b_g1 = (const float*)d_in[4];
    const float* W_f  = (const float*)d_in[5];
    const float* b_f  = (const float*)d_in[6];
    const int*   idx0 = (const int*)d_in[7];
    const int*   idx1 = (const int*)d_in[8];
    float* out = (float*)d_out;

    __bf16* U    = (__bf16*)d_ws;                         // 25.6 MB
    __bf16* V    = U   + (size_t)L_NODES * JDIM;          // 25.6 MB
    __bf16* WtH  = V   + (size_t)L_NODES * JDIM;          // 64 KB
    __bf16* WtG2 = WtH + 32768;                           // 64 KB
    __bf16* WtGv = WtG2 + 128 * 128;                      // alias: rows 128.. of WtG2

    k_prep<<<128, 256, 0, stream>>>(W_h1, W_g1, WtH, WtG2);
    k_h1uv<<<(L_NODES + 63) / 64, 256, 0, stream>>>(X, WtH, WtG2, b_h1, U, V);
    k_gfinal<<<(L_NODES + 63) / 64, 256, 0, stream>>>(U, V, WtGv, b_g1, W_f, b_f,
                                                      idx0, idx1, out);
}

// Round 8
// 249.024 us; speedup vs baseline: 1.0783x; 1.0029x over previous
//
#include <hip/hip_runtime.h>

#define L_NODES 100000
#define NFEAT   256
#define JDIM    128

typedef __bf16 bf16x8 __attribute__((ext_vector_type(8)));
typedef __bf16 bf16x4 __attribute__((ext_vector_type(4)));
typedef float  floatx4 __attribute__((ext_vector_type(4)));

// ---------------------------------------------------------------------------
// Prep:
//   WtH [128][256]: WtH[n][k]  = bf16(W_h1[k][n])
//   WtG2[256][128]: n<128: Wg[k][n]   (U cols);  n>=128: Wg[128+k][n-128] (V cols)
//     rows 128.. of WtG2 double as WtGv[n][k]=Wg[128+k][n] for k_gfinal.
// ---------------------------------------------------------------------------
__global__ __launch_bounds__(256) void k_prep(
    const float* __restrict__ Wh, const float* __restrict__ Wg,
    __bf16* __restrict__ WtH, __bf16* __restrict__ WtG2)
{
    int i = blockIdx.x * 256 + threadIdx.x;   // 32768
    int n = i >> 8, k = i & 255;
    WtH[i] = (__bf16)Wh[k * JDIM + n];
    int n2 = i >> 7, k2 = i & 127;
    WtG2[i] = (n2 < 128) ? (__bf16)Wg[k2 * JDIM + n2]
                         : (__bf16)Wg[(128 + k2) * JDIM + (n2 - 128)];
}

// ---------------------------------------------------------------------------
// Kernel 1 (fused h1+uv).  R19: BM 64 -> 128 (782 blocks).  Rationale: each
// block re-reads 128 KB of weight panels (b1+b2); at BM=64 that's 200 MB of
// request volume chip-wide — ~55% of this kernel's total and the likely gap
// vs its 24 us memory floor.  BM=128 halves it.  Geometry: one Sm[128x264]
// (67.6 KB, 2 blocks/CU) with As/Hs/Os aliased (5 barriers); all 32 X loads
// in one batched exposure; phase 2 = two ks-passes (h=0,1), both acc halves
// live, Os flushed only after all Hs reads close (alias safety).
// ---------------------------------------------------------------------------
__global__ __launch_bounds__(256, 2) void k_h1uv(
    const float* __restrict__ X, const __bf16* __restrict__ WtH,
    const __bf16* __restrict__ WtG2, const float* __restrict__ b,
    __bf16* __restrict__ U, __bf16* __restrict__ V)
{
    __shared__ __bf16 Sm[128 * 264];  // As (stride 264) / Hs (stride 136) / Os

    const int tid  = threadIdx.x;
    const int row0 = blockIdx.x * 128;
    const int wave = tid >> 6, lane = tid & 63;
    const int lm = lane & 15, lq = lane >> 4;

    // ---- stage X tile: all 32 loads in flight (NT), then cvt+write ----
    floatx4 xa[32];
    #pragma unroll
    for (int it = 0; it < 32; ++it) {
        int f4  = it * 256 + tid;                 // 0..8191
        int row = f4 >> 6, c4 = f4 & 63;
        int grow = row0 + row; if (grow >= L_NODES) grow = L_NODES - 1;
        xa[it] = __builtin_nontemporal_load(
                     reinterpret_cast<const floatx4*>(X + (size_t)grow * NFEAT + c4 * 4));
    }
    #pragma unroll
    for (int it = 0; it < 32; ++it) {
        int f4  = it * 256 + tid;
        int row = f4 >> 6, c4 = f4 & 63;
        bf16x4 o;
        o[0]=(__bf16)xa[it][0]; o[1]=(__bf16)xa[it][1];
        o[2]=(__bf16)xa[it][2]; o[3]=(__bf16)xa[it][3];
        *(bf16x4*)&Sm[row * 264 + c4 * 4] = o;
    }

    // b1 panel (phase-1 only); latency hides under the barrier.
    bf16x8 b1[2][8];
    #pragma unroll
    for (int nt = 0; nt < 2; ++nt) {
        int ntg = wave * 2 + nt;
        #pragma unroll
        for (int ks = 0; ks < 8; ++ks)
            b1[nt][ks] = *(const bf16x8*)(WtH + (size_t)(ntg * 16 + lm) * 256 + ks * 32 + lq * 8);
    }
    __syncthreads();                                          // bar1: As ready

    // ---- phase 1: H = relu(X @ Wh + b), 128 rows ----
    floatx4 acc1[8][2] = {};
    #pragma unroll
    for (int ks = 0; ks < 8; ++ks) {
        bf16x8 af[8];
        #pragma unroll
        for (int t = 0; t < 8; ++t)
            af[t] = *(const bf16x8*)&Sm[(t * 16 + lm) * 264 + ks * 32 + lq * 8];
        #pragma unroll
        for (int t = 0; t < 8; ++t)
            #pragma unroll
            for (int nt = 0; nt < 2; ++nt)
                acc1[t][nt] = __builtin_amdgcn_mfma_f32_16x16x32_bf16(
                    af[t], b1[nt][ks], acc1[t][nt], 0, 0, 0);
    }
    __syncthreads();                                          // bar2: As reads closed

    // write Hs (stride 136; aliases As — As dead)
    #pragma unroll
    for (int nt = 0; nt < 2; ++nt) {
        int col = (wave * 2 + nt) * 16 + lm;
        float bias = b[col];
        #pragma unroll
        for (int t = 0; t < 8; ++t)
            #pragma unroll
            for (int p = 0; p < 4; ++p)
                Sm[(t * 16 + lq * 4 + p) * 136 + col] =
                    (__bf16)fmaxf(acc1[t][nt][p] + bias, 0.f);
    }
    __syncthreads();                                          // bar3: Hs ready

    // ---- phase 2: two ks-passes (h=0,1); both acc halves stay live ----
    floatx4 acc2a[8][2] = {}, acc2b[8][2] = {};
    {
        bf16x8 b2h[2][4];
        #pragma unroll
        for (int nt = 0; nt < 2; ++nt) {
            int ntg = wave * 4 + nt;                          // h = 0
            #pragma unroll
            for (int ks = 0; ks < 4; ++ks)
                b2h[nt][ks] = *(const bf16x8*)(WtG2 + (size_t)(ntg * 16 + lm) * 128 + ks * 32 + lq * 8);
        }
        #pragma unroll
        for (int ks = 0; ks < 4; ++ks) {
            bf16x8 af[8];
            #pragma unroll
            for (int t = 0; t < 8; ++t)
                af[t] = *(const bf16x8*)&Sm[(t * 16 + lm) * 136 + ks * 32 + lq * 8];
            #pragma unroll
            for (int t = 0; t < 8; ++t)
                #pragma unroll
                for (int nt = 0; nt < 2; ++nt)
                    acc2a[t][nt] = __builtin_amdgcn_mfma_f32_16x16x32_bf16(
                        af[t], b2h[nt][ks], acc2a[t][nt], 0, 0, 0);
        }
    }
    {
        bf16x8 b2h[2][4];
        #pragma unroll
        for (int nt = 0; nt < 2; ++nt) {
            int ntg = wave * 4 + 2 + nt;                      // h = 1
            #pragma unroll
            for (int ks = 0; ks < 4; ++ks)
                b2h[nt][ks] = *(const bf16x8*)(WtG2 + (size_t)(ntg * 16 + lm) * 128 + ks * 32 + lq * 8);
        }
        #pragma unroll
        for (int ks = 0; ks < 4; ++ks) {
            bf16x8 af[8];
            #pragma unroll
            for (int t = 0; t < 8; ++t)
                af[t] = *(const bf16x8*)&Sm[(t * 16 + lm) * 136 + ks * 32 + lq * 8];
            #pragma unroll
            for (int t = 0; t < 8; ++t)
                #pragma unroll
                for (int nt = 0; nt < 2; ++nt)
                    acc2b[t][nt] = __builtin_amdgcn_mfma_f32_16x16x32_bf16(
                        af[t], b2h[nt][ks], acc2b[t][nt], 0, 0, 0);
        }
    }
    __syncthreads();                                          // bar4: Hs reads closed

    // write Os (stride 264; aliases Hs — Hs dead)
    #pragma unroll
    for (int h = 0; h < 2; ++h)
        #pragma unroll
        for (int nt = 0; nt < 2; ++nt) {
            int col = (wave * 4 + h * 2 + nt) * 16 + lm;
            #pragma unroll
            for (int t = 0; t < 8; ++t)
                #pragma unroll
                for (int p = 0; p < 4; ++p)
                    Sm[(t * 16 + lq * 4 + p) * 264 + col] =
                        (__bf16)(h ? acc2b[t][nt][p] : acc2a[t][nt][p]);
        }
    __syncthreads();                                          // bar5: Os ready

    // coalesced store of U|V from Os
    #pragma unroll
    for (int it = 0; it < 16; ++it) {
        int fid = it * 256 + tid;                 // 0..4095
        int row = fid >> 5, c8 = fid & 31;
        int grow = row0 + row;
        if (grow < L_NODES) {
            int col = c8 * 8;
            bf16x8 v = *(bf16x8*)&Sm[row * 264 + col];
            if (col < 128) *(bf16x8*)(U + (size_t)grow * JDIM + col) = v;
            else           *(bf16x8*)(V + (size_t)grow * JDIM + (col - 128)) = v;
        }
    }
}

// ---------------------------------------------------------------------------
// Kernel 2 (fused gather + final).  Unchanged (67.5 us; request volume
// 410 MB at ~6.1 TB/s service = the memory-system ceiling for this access
// pattern; request bytes irreducible at bf16).
// ---------------------------------------------------------------------------
__global__ __launch_bounds__(256, 4) void k_gfinal(
    const __bf16* __restrict__ U, const __bf16* __restrict__ V,
    const __bf16* __restrict__ WtGv, const float* __restrict__ bg,
    const float* __restrict__ Wf, const float* __restrict__ bf,
    const int* __restrict__ idx0, const int* __restrict__ idx1,
    float* __restrict__ out)
{
    __shared__ int    sidx[2][8][64];               // 4 KB; part[] aliases this
    __shared__ __bf16 E1s[64 * 136];                // 17.4 KB
    __shared__ __bf16 Us [64 * 136];                // 17.4 KB
    float (*part)[64][2] = (float (*)[64][2])&sidx[0][0][0];   // 2 KB alias

    const int tid  = threadIdx.x;
    const int row0 = blockIdx.x * 64;
    const int wave = tid >> 6, lane = tid & 63;
    const int lm = lane & 15, lq = lane >> 4;

    // stage indices (1024 ints, 4/thread, NT) and U tile (4 bf16x8/thread)
    #pragma unroll
    for (int it = 0; it < 4; ++it) {
        int fid = it * 256 + tid;                 // 0..1023
        int m = fid >> 9, rem = fid & 511;
        int s = rem >> 6, il = rem & 63;
        int gr = row0 + il; if (gr >= L_NODES) gr = L_NODES - 1;
        const int* ip = (m ? idx1 : idx0) + (size_t)s * L_NODES + gr;
        sidx[m][s][il] = __builtin_nontemporal_load(ip);
    }
    #pragma unroll
    for (int it = 0; it < 4; ++it) {
        int fid = it * 256 + tid;                 // 0..1023
        int r = fid >> 4, c8 = fid & 15;
        int g = row0 + r; if (g >= L_NODES) g = L_NODES - 1;
        *(bf16x8*)&Us[r * 136 + c8 * 8] = *(const bf16x8*)(U + (size_t)g * JDIM + c8 * 8);
    }
    __syncthreads();

    // ---- phase A: gather-add into E1s (2-deep pipelined) ----
    {
        const int c0 = (tid & 15) * 8;            // col chunk
        const int rb = tid >> 4;                  // row base 0..15 (+16k)
        float bias[8];
        *(float4*)&bias[0] = *(const float4*)(bg + c0);
        *(float4*)&bias[4] = *(const float4*)(bg + c0 + 4);

        float acc[4][8] = {};
        bf16x8 uA[4], vA[4], uB[4], vB[4];

        auto LOADP = [&](int s, bf16x8 (&uu)[4], bf16x8 (&vv)[4]) {
            #pragma unroll
            for (int rr = 0; rr < 4; ++rr) {
                int r = rb + rr * 16;
                int a0 = sidx[0][s][r], a1 = sidx[1][s][r];
                uu[rr] = *(const bf16x8*)(U + (size_t)a0 * JDIM + c0);
                vv[rr] = *(const bf16x8*)(V + (size_t)a1 * JDIM + c0);
            }
        };
        auto ACCUM = [&](bf16x8 (&uu)[4], bf16x8 (&vv)[4]) {
            #pragma unroll
            for (int rr = 0; rr < 4; ++rr)
                #pragma unroll
                for (int p = 0; p < 8; ++p)
                    acc[rr][p] += fmaxf((float)uu[rr][p] + (float)vv[rr][p] + bias[p], 0.f);
        };

        LOADP(0, uA, vA);
        #pragma unroll
        for (int s = 0; s < 8; ++s) {
            if ((s & 1) == 0) {
                if (s < 7) LOADP(s + 1, uB, vB);
                ACCUM(uA, vA);
            } else {
                if (s < 7) LOADP(s + 1, uA, vA);
                ACCUM(uB, vB);
            }
        }

        #pragma unroll
        for (int rr = 0; rr < 4; ++rr) {
            int r = rb + rr * 16;
            bf16x8 o;
            #pragma unroll
            for (int p = 0; p < 8; ++p)
                o[p] = (__bf16)fmaxf(acc[rr][p] * 0.125f, 0.f);
            *(bf16x8*)&E1s[r * 136 + c0] = o;
        }
    }
    __syncthreads();   // also closes all sidx reads before part[] writes

    // B panel (phase-B-only): load now so it doesn't hold VGPRs in phase A
    bf16x8 b3[2][4];
    #pragma unroll
    for (int nt = 0; nt < 2; ++nt) {
        int ntg = wave * 2 + nt;
        #pragma unroll
        for (int ks = 0; ks < 4; ++ks)
            b3[nt][ks] = *(const bf16x8*)(WtGv + (size_t)(ntg * 16 + lm) * 128 + ks * 32 + lq * 8);
    }

    // ---- phase B: E2 = relu(U + E1 @ Wg_bot + bg); head ----
    floatx4 acc[4][2] = {};
    #pragma unroll
    for (int ks = 0; ks < 4; ++ks) {
        bf16x8 af[4];
        #pragma unroll
        for (int t = 0; t < 4; ++t)
            af[t] = *(const bf16x8*)&E1s[(t * 16 + lm) * 136 + ks * 32 + lq * 8];
        #pragma unroll
        for (int t = 0; t < 4; ++t)
            #pragma unroll
            for (int nt = 0; nt < 2; ++nt)
                acc[t][nt] = __builtin_amdgcn_mfma_f32_16x16x32_bf16(
                    af[t], b3[nt][ks], acc[t][nt], 0, 0, 0);
    }

    float bias[2], wf0[2], wf1[2];
    #pragma unroll
    for (int nt = 0; nt < 2; ++nt) {
        int col = (wave * 2 + nt) * 16 + lm;
        bias[nt] = bg[col];
        wf0[nt] = Wf[col * 2 + 0];
        wf1[nt] = Wf[col * 2 + 1];
    }
    #pragma unroll
    for (int t = 0; t < 4; ++t) {
        float p0[4], p1[4];
        #pragma unroll
        for (int p = 0; p < 4; ++p) {
            int r = t * 16 + lq * 4 + p;
            float a0 = 0.f, a1 = 0.f;
            #pragma unroll
            for (int nt = 0; nt < 2; ++nt) {
                int col = (wave * 2 + nt) * 16 + lm;
                float e2 = fmaxf((float)Us[r * 136 + col] + acc[t][nt][p] + bias[nt], 0.f);
                a0 = fmaf(e2, wf0[nt], a0);
                a1 = fmaf(e2, wf1[nt], a1);
            }
            p0[p] = a0; p1[p] = a1;
        }
        #pragma unroll
        for (int m = 1; m <= 8; m <<= 1)
            #pragma unroll
            for (int p = 0; p < 4; ++p) {
                p0[p] += __shfl_xor(p0[p], m, 16);
                p1[p] += __shfl_xor(p1[p], m, 16);
            }
        if (lm == 0)
            #pragma unroll
            for (int p = 0; p < 4; ++p) {
                part[wave][t * 16 + lq * 4 + p][0] = p0[p];
                part[wave][t * 16 + lq * 4 + p][1] = p1[p];
            }
    }
    __syncthreads();

    if (tid < 128) {
        int row = tid >> 1, o = tid & 1;
        int grow = row0 + row;
        if (grow < L_NODES) {
            float v = part[0][row][o] + part[1][row][o] + part[2][row][o]
                    + part[3][row][o] + bf[o];
            __builtin_nontemporal_store(v, &out[(size_t)grow * 2 + o]);
        }
    }
}

// ---------------------------------------------------------------------------
extern "C" void kernel_launch(void* const* d_in, const int* in_sizes, int n_in,
                              void* d_out, int out_size, void* d_ws, size_t ws_size,
                              hipStream_t stream) {
    const float* X    = (const float*)d_in[0];
    const float* W_h1 = (const float*)d_in[1];
    const float* b_h1 = (const float*)d_in[2];
    const float* W_g1 = (const float*)d_in[3];
    const float* b_g1 = (const float*)d_in[4];
    const float* W_f  = (const float*)d_in[5];
    const float* b_f  = (const float*)d_in[6];
    const int*   idx0 = (const int*)d_in[7];
    const int*   idx1 = (const int*)d_in[8];
    float* out = (float*)d_out;

    __bf16* U    = (__bf16*)d_ws;                         // 25.6 MB
    __bf16* V    = U   + (size_t)L_NODES * JDIM;          // 25.6 MB
    __bf16* WtH  = V   + (size_t)L_NODES * JDIM;          // 64 KB
    __bf16* WtG2 = WtH + 32768;                           // 64 KB
    __bf16* WtGv = WtG2 + 128 * 128;                      // alias: rows 128.. of WtG2

    k_prep<<<128, 256, 0, stream>>>(W_h1, W_g1, WtH, WtG2);
    k_h1uv<<<(L_NODES + 127) / 128, 256, 0, stream>>>(X, WtH, WtG2, b_h1, U, V);
    k_gfinal<<<(L_NODES + 63) / 64, 256, 0, stream>>>(U, V, WtGv, b_g1, W_f, b_f,
                                                      idx0, idx1, out);
}